// Round 1
// 400.745 us; speedup vs baseline: 1.0816x; 1.0816x over previous
//
#include <hip/hip_runtime.h>
#include <hip/hip_bf16.h>
#include <cstdint>
#include <cstddef>

#define BATCH 2
#define S_LEN 2048
#define HID   2048
#define NH    16
#define HD    128
#define GK    2048          // K of all projections
#define NT    (GK / 64)     // 32 K-tiles of 64
#define NIT   (NT / 2)      // 16 iterations, 2 K-tiles each
#define ATT_TILES (32 * NH * BATCH)   // 32 q-tiles x 32 (b,h) = 1024

typedef short bf16x8 __attribute__((ext_vector_type(8)));
typedef float f32x4  __attribute__((ext_vector_type(4)));

__device__ inline unsigned short f2bf(float f) {
    unsigned int u = __float_as_uint(f);
    unsigned int r = (u + 0x7fffu + ((u >> 16) & 1u)) >> 16;
    return (unsigned short)r;
}

// ---------------- fp32 -> bf16 convert, 8 elems/thread ----------------
__global__ __launch_bounds__(256) void conv_f32_bf16(const float* __restrict__ src,
                                                     unsigned short* __restrict__ dst,
                                                     long n) {
    long i = ((long)blockIdx.x * 256 + threadIdx.x) * 8;
    if (i >= n) return;
    const float4 a = *(const float4*)(src + i);
    const float4 b = *(const float4*)(src + i + 4);
    union { unsigned short u[8]; bf16x8 v; } o;
    o.u[0] = f2bf(a.x); o.u[1] = f2bf(a.y); o.u[2] = f2bf(a.z); o.u[3] = f2bf(a.w);
    o.u[4] = f2bf(b.x); o.u[5] = f2bf(b.y); o.u[6] = f2bf(b.z); o.u[7] = f2bf(b.w);
    *(bf16x8*)(dst + i) = o.v;
}

__global__ __launch_bounds__(256) void conv4_f32_bf16(const float* __restrict__ s0,
                                                      const float* __restrict__ s1,
                                                      const float* __restrict__ s2,
                                                      const float* __restrict__ s3,
                                                      unsigned short* __restrict__ d0,
                                                      unsigned short* __restrict__ d1,
                                                      unsigned short* __restrict__ d2,
                                                      unsigned short* __restrict__ d3,
                                                      long n) {
    const int z = blockIdx.y;
    const float* src = (z == 0) ? s0 : (z == 1) ? s1 : (z == 2) ? s2 : s3;
    unsigned short* dst = (z == 0) ? d0 : (z == 1) ? d1 : (z == 2) ? d2 : d3;
    long i = ((long)blockIdx.x * 256 + threadIdx.x) * 8;
    if (i >= n) return;
    const float4 a = *(const float4*)(src + i);
    const float4 b = *(const float4*)(src + i + 4);
    union { unsigned short u[8]; bf16x8 v; } o;
    o.u[0] = f2bf(a.x); o.u[1] = f2bf(a.y); o.u[2] = f2bf(a.z); o.u[3] = f2bf(a.w);
    o.u[4] = f2bf(b.x); o.u[5] = f2bf(b.y); o.u[6] = f2bf(b.z); o.u[7] = f2bf(b.w);
    *(bf16x8*)(dst + i) = o.v;
}

__global__ void zero_int(int* p) { *p = 0; }

// =====================================================================
// 256x256 8-phase GEMM (guide §5 template: T2 swizzle + T3/T4 counted
// vmcnt + T5 setprio).  C = A(row-major MxK) . B^T (B row-major NxK).
// 512 threads = 8 waves (2M x 4N), per-wave output 128x64, BK=64.
// LDS 128 KiB: buf d: A at d*32768(u16), B at d*32768+16384; half=8192.
// K-loop iteration = 2 K-tiles, 8 phases; each phase: {ds_read subtile,
// stage 1 half-tile (2x global_load_lds dwordx4), barrier, lgkmcnt(0),
// setprio(1) 16xMFMA setprio(0), [vmcnt(4) @P4/P8], barrier}.
// vmcnt(4) trace (steady state, 12 loads max in flight):
//  P4: queue=[T(2i+1).A0,A1 (prev P8), T(2i+1).B0,B1 (P1,P2),
//             T(2i+2).B0,B1 (P3,P4)] -> drain 8 oldest = T(2i+1) done.
//  P8: queue=[T(2i+2).B0,B1, T(2i+2).A0,A1 (P5,P6),
//             T(2i+3).A0,A1 (P8 burst)] -> drain 8 = T(2i+2) done.
// Swizzle: LDS[r][chunk16B c] holds global[r][c ^ (r&7)] (pre-swizzled
// source addr, linear global_load_lds dest); reads XOR back with ln&7.
// =====================================================================

#define STAGE(DU, SRC, KT, H) do {                                            \
    const unsigned short* _s0 = (SRC) + (size_t)((H) * 128) * GK + (KT) * 64; \
    __builtin_amdgcn_global_load_lds(                                         \
        (const __attribute__((address_space(1))) void*)_s0,                   \
        (__attribute__((address_space(3))) void*)(Sm + (DU) + (H) * 8192 + sdst), \
        16, 0, 0);                                                            \
    __builtin_amdgcn_global_load_lds(                                         \
        (const __attribute__((address_space(1))) void*)(_s0 + (size_t)64 * GK), \
        (__attribute__((address_space(3))) void*)(Sm + (DU) + (H) * 8192 + 4096 + sdst), \
        16, 0, 0);                                                            \
} while (0)

#define READ_A(D, HI) do { _Pragma("unroll")                                  \
    for (int mi = 0; mi < 4; ++mi) {                                          \
        const int r_ = wm * 128 + (HI) * 64 + mi * 16 + ln;                   \
        a[mi][0] = *(const bf16x8*)&Sm[(D) * 32768 + r_ * 64 + sw0];          \
        a[mi][1] = *(const bf16x8*)&Sm[(D) * 32768 + r_ * 64 + sw1];          \
    } } while (0)

#define READ_B(D, SEL) do { _Pragma("unroll")                                 \
    for (int ni = 0; ni < 2; ++ni) {                                          \
        const int r_ = wn * 64 + ((SEL) * 2 + ni) * 16 + ln;                  \
        b[(SEL)*2+ni][0] = *(const bf16x8*)&Sm[(D) * 32768 + 16384 + r_ * 64 + sw0]; \
        b[(SEL)*2+ni][1] = *(const bf16x8*)&Sm[(D) * 32768 + 16384 + r_ * 64 + sw1]; \
    } } while (0)

#define MFMA16(MB, NS) do { _Pragma("unroll")                                 \
    for (int mi = 0; mi < 4; ++mi) _Pragma("unroll")                          \
    for (int ni = 0; ni < 2; ++ni) _Pragma("unroll")                          \
    for (int ks = 0; ks < 2; ++ks)                                            \
        acc[(MB)+mi][(NS)*2+ni] = __builtin_amdgcn_mfma_f32_16x16x32_bf16(    \
            a[mi][ks], b[(NS)*2+ni][ks], acc[(MB)+mi][(NS)*2+ni], 0, 0, 0);   \
} while (0)

#define PH_BEGIN  __builtin_amdgcn_s_barrier();                               \
                  asm volatile("s_waitcnt lgkmcnt(0)" ::: "memory");          \
                  __builtin_amdgcn_s_setprio(1)
#define PH_END    __builtin_amdgcn_s_setprio(0); __builtin_amdgcn_s_barrier()
#define PH_END_V4 __builtin_amdgcn_s_setprio(0);                              \
                  asm volatile("s_waitcnt vmcnt(4)" ::: "memory");            \
                  __builtin_amdgcn_s_barrier()

// mode 0: bf16 -> [b,h,s,d]; mode 1: bf16 -> [b,h,d,s] (LDS repack);
// mode 2: fp32 -> [m][HID]
__device__ __forceinline__ void gemm256_core(const unsigned short* __restrict__ A,
                                             const unsigned short* __restrict__ Bw,
                                             const float* __restrict__ bias,
                                             void* __restrict__ Cout,
                                             int mode, int M0, int N0,
                                             unsigned short* Sm) {
    const int tid  = threadIdx.x;
    const int lane = tid & 63;
    const int wave = tid >> 6;
    const int ln = lane & 15, g = lane >> 4;
    const int wm = wave & 1, wn = wave >> 1;

    // staging: thread covers row (tid>>3), pre-swizzled source column
    const int strow = tid >> 3;
    const int stcol = (((tid & 7) ^ ((tid >> 3) & 7)) << 3);
    const unsigned short* gA = A  + (size_t)(M0 + strow) * GK + stcol;
    const unsigned short* gB = Bw + (size_t)(N0 + strow) * GK + stcol;
    const int sdst = wave * 512;            // u16 offset of wave's 1KB slice

    // swizzled LDS read column (u16) for k-slice 0/1: slot = ks*4+g
    const int sw0 = ((g    ) ^ (ln & 7)) << 3;
    const int sw1 = ((g + 4) ^ (ln & 7)) << 3;

    f32x4 acc[8][4];
#pragma unroll
    for (int i = 0; i < 8; ++i)
#pragma unroll
        for (int j = 0; j < 4; ++j) acc[i][j] = (f32x4){0.f, 0.f, 0.f, 0.f};
    bf16x8 a[4][2], b[4][2];

    // prologue: T0 full + T1.A  (12 loads) -> wait T0 (leave T1.A in flight)
    STAGE(0,     gA, 0, 0); STAGE(0,     gA, 0, 1);
    STAGE(16384, gB, 0, 0); STAGE(16384, gB, 0, 1);
    STAGE(32768, gA, 1, 0); STAGE(32768, gA, 1, 1);
    asm volatile("s_waitcnt vmcnt(4)" ::: "memory");
    __builtin_amdgcn_s_barrier();

    for (int it = 0; it < NIT; ++it) {
        const int kt1 = 2 * it + 1;
        const int kt2 = (2 * it + 2 < NT) ? 2 * it + 2 : NT - 1;  // clamp: tail garbage never read
        const int kt3 = (2 * it + 3 < NT) ? 2 * it + 3 : NT - 1;
        // P1: buf0 reads part1; stage T(2i+1).B0 -> buf1.B
        READ_A(0, 0); READ_B(0, 0);
        STAGE(49152, gB, kt1, 0);
        PH_BEGIN; MFMA16(0, 0); PH_END;
        // P2
        READ_B(0, 1);
        STAGE(49152, gB, kt1, 1);
        PH_BEGIN; MFMA16(0, 1); PH_END;
        // P3: buf0.B free after P2 -> stage T(2i+2).B0
        READ_A(0, 1);
        STAGE(16384, gB, kt2, 0);
        PH_BEGIN; MFMA16(4, 0); PH_END;
        // P4
        STAGE(16384, gB, kt2, 1);
        PH_BEGIN; MFMA16(4, 1); PH_END_V4;   // T(2i+1) now resident
        // P5: buf1 reads part1; buf0.A free after P3 -> stage T(2i+2).A0
        READ_A(1, 0); READ_B(1, 0);
        STAGE(0, gA, kt2, 0);
        PH_BEGIN; MFMA16(0, 0); PH_END;
        // P6
        READ_B(1, 1);
        STAGE(0, gA, kt2, 1);
        PH_BEGIN; MFMA16(0, 1); PH_END;
        // P7 (no stage: buf1.A still being read)
        READ_A(1, 1);
        PH_BEGIN; MFMA16(4, 0); PH_END;
        // P8: buf1.A free -> burst both T(2i+3).A halves
        STAGE(32768, gA, kt3, 0); STAGE(32768, gA, kt3, 1);
        PH_BEGIN; MFMA16(4, 1); PH_END_V4;   // T(2i+2) now resident
    }
    asm volatile("s_waitcnt vmcnt(0)" ::: "memory");  // drain tail prefetches before LDS reuse
    __syncthreads();

    if (mode == 0) {
        // bf16 -> [b, h, s, d]
        const int bb = M0 >> 11;
        const int sb = M0 & (S_LEN - 1);
#pragma unroll
        for (int nf = 0; nf < 4; ++nf) {
            const int n = N0 + wn * 64 + nf * 16 + ln;
            const float bn = bias[n];
            const int h = n >> 7, d = n & (HD - 1);
            unsigned short* dst = (unsigned short*)Cout +
                (((size_t)(bb * NH + h) * S_LEN + sb + wm * 128) * HD + d);
#pragma unroll
            for (int mf = 0; mf < 8; ++mf)
#pragma unroll
                for (int r = 0; r < 4; ++r)
                    dst[(size_t)(mf * 16 + g * 4 + r) * HD] = f2bf(acc[mf][nf][r] + bn);
        }
    } else if (mode == 2) {
        float* dst = (float*)Cout;
#pragma unroll
        for (int nf = 0; nf < 4; ++nf) {
            const int n = N0 + wn * 64 + nf * 16 + ln;
            const float bn = bias[n];
#pragma unroll
            for (int mf = 0; mf < 8; ++mf)
#pragma unroll
                for (int r = 0; r < 4; ++r) {
                    const int m = M0 + wm * 128 + mf * 16 + g * 4 + r;
                    dst[(size_t)m * HID + n] = acc[mf][nf][r] + bn;
                }
        }
    } else {
        // mode 1: bf16 -> [b, h, d, s] via LDS repack, 2 passes of 128 d-cols.
        // LDS [128][256] u16, chunk(8xu16) swizzle cs = (s>>3) ^ (d&31).
        const int bb = M0 >> 11;
        const int sb = M0 & (S_LEN - 1);
#pragma unroll
        for (int p = 0; p < 2; ++p) {
            if ((wn >> 1) == p) {
#pragma unroll
                for (int nf = 0; nf < 4; ++nf) {
                    const int dl = (wn & 1) * 64 + nf * 16 + ln;
                    const float bn = bias[N0 + p * 128 + dl];
#pragma unroll
                    for (int mf = 0; mf < 8; ++mf) {
                        const int sl = wm * 128 + mf * 16 + g * 4;   // r in [0,4) same chunk
                        const int cs = (sl >> 3) ^ (dl & 31);
                        union { unsigned short u[4]; unsigned long long q; } pk;
#pragma unroll
                        for (int r = 0; r < 4; ++r) pk.u[r] = f2bf(acc[mf][nf][r] + bn);
                        *(unsigned long long*)&Sm[dl * 256 + cs * 8 + (sl & 7)] = pk.q;
                    }
                }
            }
            __syncthreads();
            {
                const int dl = tid >> 2;
                const int h = (N0 >> 7) + p;
                unsigned short* dst = (unsigned short*)Cout +
                    ((size_t)(bb * NH + h) * HD + dl) * S_LEN + sb;
#pragma unroll
                for (int jj = 0; jj < 8; ++jj) {
                    const int sc = (tid & 3) + jj * 4;    // 4 threads -> 64B contiguous
                    const int cs = sc ^ (dl & 31);
                    *(bf16x8*)(dst + sc * 8) = *(const bf16x8*)&Sm[dl * 256 + cs * 8];
                }
            }
            __syncthreads();
        }
    }
}

__global__ __launch_bounds__(512, 2) void gemm_qkv256(
        const unsigned short* __restrict__ A,
        const unsigned short* __restrict__ w0, const unsigned short* __restrict__ w1,
        const unsigned short* __restrict__ w2,
        const float* __restrict__ b0, const float* __restrict__ b1,
        const float* __restrict__ b2,
        void* o0, void* o1, void* o2) {
    extern __shared__ __align__(16) unsigned short Sm[];
    const int z = blockIdx.z;
    const unsigned short* Bw = (z == 0) ? w0 : (z == 1) ? w1 : w2;
    const float* bias = (z == 0) ? b0 : (z == 1) ? b1 : b2;
    void* Cout = (z == 0) ? o0 : (z == 1) ? o1 : o2;
    gemm256_core(A, Bw, bias, Cout, (z == 2) ? 1 : 0,
                 blockIdx.y * 256, blockIdx.x * 256, Sm);
}

__global__ __launch_bounds__(512, 2) void gemm_out256(
        const unsigned short* __restrict__ A, const unsigned short* __restrict__ Bw,
        const float* __restrict__ bias, float* __restrict__ Cout) {
    extern __shared__ __align__(16) unsigned short Sm[];
    gemm256_core(A, Bw, bias, Cout, 2, blockIdx.y * 256, blockIdx.x * 256, Sm);
}

// ---------------- causal flash attention, LDS-staged K/V (swizzled) ----------
// (unchanged from previous round)
__global__ __launch_bounds__(256) void attn_kernel(const unsigned short* __restrict__ Q,
                                                   const unsigned short* __restrict__ Kk,
                                                   const unsigned short* __restrict__ Vt,
                                                   unsigned short* __restrict__ O,
                                                   int* __restrict__ ticket) {
    __shared__ __align__(16) unsigned short Ks[64 * 128];    // [key][d], chunk^=(key&15)
    __shared__ __align__(16) unsigned short Vs[144 * 64];    // [d][key], chunk^=(d&7); 128..143 ones
    __shared__ __align__(16) unsigned short Pl[4][16 * 72];  // per-wave P, stride 72
    __shared__ int tsh;
    const int tid = threadIdx.x;
    const int lane = tid & 63;
    const int wave = tid >> 6;
    const int g = lane >> 4, ln = lane & 15;
    const float scale2 = 0.08838834764831845f * 1.4426950408889634f;  // 1/sqrt(128)*log2(e)

    for (int i = tid; i < 16 * 64; i += 256) Vs[128 * 64 + i] = 0x3F80;

    const int kcol = ((tid & 15) ^ ((tid >> 4) & 15)) * 8;   // K: 16 chunks/row
    const int vcol = ((tid & 7) ^ ((tid >> 3) & 7)) * 8;     // V: 8 chunks/row

    for (;;) {
        if (tid == 0) tsh = atomicAdd(ticket, 1);
        __syncthreads();
        const int t = tsh;
        if (t >= ATT_TILES) break;
        const int qt = 31 - (t >> 5);       // LPT: big q-tiles first
        const int bh = t & 31;
        const int qbase = qt * 64 + wave * 16;

        const unsigned short* Qp = Q  + (size_t)bh * S_LEN * HD;
        const unsigned short* Kp = Kk + (size_t)bh * S_LEN * HD;
        const unsigned short* Vp = Vt + (size_t)bh * HD * S_LEN;

        bf16x8 aq[4];
#pragma unroll
        for (int dc = 0; dc < 4; ++dc)
            aq[dc] = *(const bf16x8*)&Qp[(size_t)(qbase + ln) * HD + dc * 32 + g * 8];

        f32x4 acc[9];
#pragma unroll
        for (int i = 0; i < 9; ++i) acc[i] = (f32x4){0.f, 0.f, 0.f, 0.f};

        for (int kt = 0; kt <= qt; ++kt) {
            const int kb = kt * 64;
#pragma unroll
            for (int i = 0; i < 4; ++i) {
                const unsigned short* gk = Kp + (size_t)(kb + i * 16 + (tid >> 4)) * HD + kcol;
                __builtin_amdgcn_global_load_lds(
                    (const __attribute__((address_space(1))) void*)gk,
                    (__attribute__((address_space(3))) void*)(Ks + i * 2048 + wave * 512),
                    16, 0, 0);
            }
#pragma unroll
            for (int i = 0; i < 4; ++i) {
                const unsigned short* gv = Vp + (size_t)(i * 32 + (tid >> 3)) * S_LEN + kb + vcol;
                __builtin_amdgcn_global_load_lds(
                    (const __attribute__((address_space(1))) void*)gv,
                    (__attribute__((address_space(3))) void*)(Vs + i * 2048 + wave * 512),
                    16, 0, 0);
            }
            __syncthreads();
            f32x4 sc[4];
#pragma unroll
            for (int nc = 0; nc < 4; ++nc) {
                sc[nc] = (f32x4){0.f, 0.f, 0.f, 0.f};
#pragma unroll
                for (int dc = 0; dc < 4; ++dc) {
                    bf16x8 bk = *(const bf16x8*)&Ks[(nc * 16 + ln) * 128 + ((dc * 4 + g) ^ ln) * 8];
                    sc[nc] = __builtin_amdgcn_mfma_f32_16x16x32_bf16(aq[dc], bk, sc[nc], 0, 0, 0);
                }
            }
            const bool diag = (kt == qt);
#pragma unroll
            for (int nc = 0; nc < 4; ++nc)
#pragma unroll
                for (int r = 0; r < 4; ++r) {
                    float pv = __builtin_amdgcn_exp2f(sc[nc][r] * scale2);
                    if (diag && (nc * 16 + ln > wave * 16 + g * 4 + r)) pv = 0.f;
                    Pl[wave][(g * 4 + r) * 72 + nc * 16 + ln] = f2bf(pv);
                }
#pragma unroll
            for (int kc = 0; kc < 2; ++kc) {
                bf16x8 ap = *(const bf16x8*)&Pl[wave][ln * 72 + kc * 32 + g * 8];
#pragma unroll
                for (int d2 = 0; d2 < 9; ++d2) {
                    bf16x8 bv = *(const bf16x8*)&Vs[(d2 * 16 + ln) * 64 + ((kc * 4 + g) ^ (ln & 7)) * 8];
                    acc[d2] = __builtin_amdgcn_mfma_f32_16x16x32_bf16(ap, bv, acc[d2], 0, 0, 0);
                }
            }
            __syncthreads();
        }
        const int b = bh >> 4, h = bh & 15;
        float inv[4];
#pragma unroll
        for (int r = 0; r < 4; ++r) inv[r] = 1.0f / acc[8][r];
#pragma unroll
        for (int d2 = 0; d2 < 8; ++d2)
#pragma unroll
            for (int r = 0; r < 4; ++r) {
                const int row = qbase + g * 4 + r;
                const int col = h * HD + d2 * 16 + ln;
                O[((size_t)b * S_LEN + row) * HID + col] = f2bf(acc[d2][r] * inv[r]);
            }
    }
}

extern "C" void kernel_launch(void* const* d_in, const int* in_sizes, int n_in,
                              void* d_out, int out_size, void* d_ws, size_t ws_size,
                              hipStream_t stream) {
    const float* x  = (const float*)d_in[0];
    const float* wq = (const float*)d_in[1];
    const float* bq = (const float*)d_in[2];
    const float* wk = (const float*)d_in[3];
    const float* bk = (const float*)d_in[4];
    const float* wv = (const float*)d_in[5];
    const float* bv = (const float*)d_in[6];
    const float* wo = (const float*)d_in[7];
    const float* bo = (const float*)d_in[8];
    float* out = (float*)d_out;

    const long nx = (long)BATCH * S_LEN * HID;  // 8388608
    const long nw = (long)HID * HID;            // 4194304

    char* p = (char*)d_ws;
    unsigned short* xb  = (unsigned short*)p; p += nx * 2;
    unsigned short* wqb = (unsigned short*)p; p += nw * 2;
    unsigned short* wkb = (unsigned short*)p; p += nw * 2;
    unsigned short* wvb = (unsigned short*)p; p += nw * 2;
    unsigned short* wob = (unsigned short*)p; p += nw * 2;
    unsigned short* Qb  = (unsigned short*)p; p += nx * 2;
    unsigned short* Kb  = (unsigned short*)p; p += nx * 2;
    unsigned short* Vtb = (unsigned short*)p; p += nx * 2;
    unsigned short* Ob  = (unsigned short*)p; p += nx * 2;
    int* ticket = (int*)p;

    conv_f32_bf16<<<(int)(nx / 8 / 256), 256, 0, stream>>>(x, xb, nx);
    dim3 cgrid((unsigned)(nw / 8 / 256), 4);
    conv4_f32_bf16<<<cgrid, 256, 0, stream>>>(wq, wk, wv, wo, wqb, wkb, wvb, wob, nw);
    zero_int<<<1, 1, 0, stream>>>(ticket);

    const int M = BATCH * S_LEN;  // 4096
    dim3 qkvgrid(HID / 256, M / 256, 3);   // 8 x 16 x 3 = 384 blocks
    gemm_qkv256<<<qkvgrid, 512, 131072, stream>>>(xb, wqb, wkb, wvb, bq, bk, bv,
                                                  Qb, Kb, Vtb);

    attn_kernel<<<768, 256, 0, stream>>>(Qb, Kb, Vtb, Ob, ticket);

    dim3 ogrid(HID / 256, M / 256);        // 8 x 16 = 128 blocks
    gemm_out256<<<ogrid, 512, 131072, stream>>>(Ob, wob, bo, out);
}